// Round 1
// baseline (298.204 us; speedup 1.0000x reference)
//
#include <hip/hip_runtime.h>

// Batched Kalman predict: x_hat = Ap x ; P_hat = Ap P Ap^T + Q
// Ap = triu(relu(A)) is wave-uniform -> held in SGPRs via readfirstlane.
// One thread per batch element; P[b] = 64 contiguous floats -> float4 I/O.

__global__ __launch_bounds__(256) void kalman_predict_kernel(
    const float* __restrict__ x,
    const float* __restrict__ P,
    const float* __restrict__ A,
    const float* __restrict__ sigp_ptr,
    const float* __restrict__ sigv_ptr,
    float* __restrict__ x_hat,
    float* __restrict__ P_hat,
    int B)
{
    // ---- Ap = triu(relu(A)), uniform across the wave: force into SGPRs ----
    float ap[64];
#pragma unroll
    for (int t = 0; t < 64; ++t) {
        float a = A[t];
        a = fmaxf(a, 0.0f);
        int r = t >> 3, c = t & 7;
        if (c < r) a = 0.0f;                 // triu
        ap[t] = __int_as_float(__builtin_amdgcn_readfirstlane(__float_as_int(a)));
    }
    float sigma_p = __int_as_float(__builtin_amdgcn_readfirstlane(__float_as_int(sigp_ptr[0])));
    float sigma_v = __int_as_float(__builtin_amdgcn_readfirstlane(__float_as_int(sigv_ptr[0])));

    int b = blockIdx.x * blockDim.x + threadIdx.x;
    if (b >= B) return;

    // ---- load x[b] (8 floats, 32B aligned) ----
    const float4* x4 = (const float4*)(x + (size_t)b * 8);
    float4 xa = x4[0], xb = x4[1];
    float xv[8] = {xa.x, xa.y, xa.z, xa.w, xb.x, xb.y, xb.z, xb.w};

    // ---- x_hat = Ap x ----
    float xh[8];
#pragma unroll
    for (int i = 0; i < 8; ++i) {
        float s = 0.0f;
#pragma unroll
        for (int j = 0; j < 8; ++j) s = fmaf(ap[i * 8 + j], xv[j], s);
        xh[i] = s;
    }
    float4* xo4 = (float4*)(x_hat + (size_t)b * 8);
    xo4[0] = make_float4(xh[0], xh[1], xh[2], xh[3]);
    xo4[1] = make_float4(xh[4], xh[5], xh[6], xh[7]);

    // ---- Q diagonal from original x ----
    float h = xv[2], w = xv[3];
    float xp = h * sigma_p, yp = w * sigma_p;
    float xvel = h * sigma_v, yv = w * sigma_v;
    float qd[8] = {xp * xp, yp * yp, xp * xp, yp * yp,
                   xvel * xvel, yv * yv, xvel * xvel, yv * yv};

    // ---- load P[b] (64 contiguous floats, 256B) ----
    float p[64];
    const float4* P4 = (const float4*)(P + (size_t)b * 64);
#pragma unroll
    for (int q = 0; q < 16; ++q) {
        float4 v = P4[q];
        p[q * 4 + 0] = v.x; p[q * 4 + 1] = v.y;
        p[q * 4 + 2] = v.z; p[q * 4 + 3] = v.w;
    }

    // ---- P_hat = Ap P Ap^T + Q, row by row ----
    float4* po4 = (float4*)(P_hat + (size_t)b * 64);
#pragma unroll
    for (int i = 0; i < 8; ++i) {
        float t[8];
#pragma unroll
        for (int k = 0; k < 8; ++k) {
            float s = 0.0f;
#pragma unroll
            for (int j = 0; j < 8; ++j) s = fmaf(ap[i * 8 + j], p[j * 8 + k], s);
            t[k] = s;
        }
        float o[8];
#pragma unroll
        for (int l = 0; l < 8; ++l) {
            float s = (l == i) ? qd[i] : 0.0f;
#pragma unroll
            for (int k = 0; k < 8; ++k) s = fmaf(t[k], ap[l * 8 + k], s);
            o[l] = s;
        }
        po4[i * 2 + 0] = make_float4(o[0], o[1], o[2], o[3]);
        po4[i * 2 + 1] = make_float4(o[4], o[5], o[6], o[7]);
    }
}

extern "C" void kernel_launch(void* const* d_in, const int* in_sizes, int n_in,
                              void* d_out, int out_size, void* d_ws, size_t ws_size,
                              hipStream_t stream) {
    const float* x  = (const float*)d_in[0];
    const float* P  = (const float*)d_in[1];
    const float* A  = (const float*)d_in[2];
    const float* sp = (const float*)d_in[3];
    const float* sv = (const float*)d_in[4];

    int B = in_sizes[0] / 8;           // x is (B, 8, 1)
    float* x_hat = (float*)d_out;      // B*8 floats
    float* P_hat = (float*)d_out + (size_t)B * 8;  // B*64 floats

    int block = 256;
    int grid = (B + block - 1) / block;
    kalman_predict_kernel<<<grid, block, 0, stream>>>(x, P, A, sp, sv, x_hat, P_hat, B);
}

// Round 2
// 251.453 us; speedup vs baseline: 1.1859x; 1.1859x over previous
//
#include <hip/hip_runtime.h>

// Batched Kalman predict: x_hat = Ap x ; P_hat = Ap P Ap^T + Q
// 8 threads per element, one P-row per thread -> every global access from a
// wave covers a contiguous 2KB span (full cache-line utilization, write merge).
// Cross-row mixing (left-multiply by Ap) staged through LDS.
//
// LDS layout: element stride 100 dwords (== 4 mod 32), row stride 12 dwords.
// Read instruction (fixed j): bank starts = (4*d + 12*j) mod 32, d=0..7 within
// a wave -> 8 distinct starts, all 32 banks, conflict-free b128.

#define ROW_STRIDE 12
#define ELEM_STRIDE 100
#define ELEMS_PER_BLOCK 32   // 256 threads / 8 rows

__global__ __launch_bounds__(256) void kalman_predict_kernel(
    const float* __restrict__ x,
    const float* __restrict__ P,
    const float* __restrict__ A,
    const float* __restrict__ sigp_ptr,
    const float* __restrict__ sigv_ptr,
    float* __restrict__ x_hat,
    float* __restrict__ P_hat,
    int B)
{
    __shared__ float lds_m[ELEMS_PER_BLOCK * ELEM_STRIDE];

    // ---- Ap = triu(relu(A)), wave-uniform -> SGPRs ----
    float ap[64];
#pragma unroll
    for (int t = 0; t < 64; ++t) {
        float a = fmaxf(A[t], 0.0f);
        if ((t & 7) < (t >> 3)) a = 0.0f;   // triu
        ap[t] = __int_as_float(__builtin_amdgcn_readfirstlane(__float_as_int(a)));
    }
    float sigma_p = __int_as_float(__builtin_amdgcn_readfirstlane(__float_as_int(sigp_ptr[0])));
    float sigma_v = __int_as_float(__builtin_amdgcn_readfirstlane(__float_as_int(sigv_ptr[0])));

    int tid = blockIdx.x * blockDim.x + threadIdx.x;
    int e = tid >> 3;          // batch element
    int r = tid & 7;           // row within element
    int e_l = threadIdx.x >> 3; // element slot within block (0..31)

    bool valid = (e < B);
    int e_c = valid ? e : (B - 1);   // clamp loads; stores predicated

    // ---- own P row (32B, wave covers contiguous 2KB via 2 insts) ----
    const float4* prow = (const float4*)(P + (size_t)e_c * 64 + r * 8);
    float4 pa = prow[0], pb = prow[1];
    float p[8] = {pa.x, pa.y, pa.z, pa.w, pb.x, pb.y, pb.z, pb.w};

    // ---- own x (all 8 values; 8 lanes share the same 32B -> L1 broadcast) ----
    const float4* xrow = (const float4*)(x + (size_t)e_c * 8);
    float4 x0 = xrow[0], x1 = xrow[1];
    float xv[8] = {x0.x, x0.y, x0.z, x0.w, x1.x, x1.y, x1.z, x1.w};

    // ---- per-lane Ap row r (VGPRs; runtime-r indexing forbids SGPR array) ----
    const float4* arow = (const float4*)(A + r * 8);
    float4 a0 = arow[0], a1 = arow[1];
    float apr[8] = {a0.x, a0.y, a0.z, a0.w, a1.x, a1.y, a1.z, a1.w};
#pragma unroll
    for (int j = 0; j < 8; ++j) {
        float v = fmaxf(apr[j], 0.0f);
        apr[j] = (j >= r) ? v : 0.0f;   // triu row mask
    }

    // ---- step 1: M row r = P row r * Ap^T : m[l] = sum_k p[k]*ap[l][k] ----
    float m[8];
#pragma unroll
    for (int l = 0; l < 8; ++l) {
        float s = 0.0f;
#pragma unroll
        for (int k = 0; k < 8; ++k) s = fmaf(ap[l * 8 + k], p[k], s);
        m[l] = s;
    }

    // ---- stage M row in LDS ----
    float* slot = lds_m + e_l * ELEM_STRIDE + r * ROW_STRIDE;
    ((float4*)slot)[0] = make_float4(m[0], m[1], m[2], m[3]);
    ((float4*)(slot + 4))[0] = make_float4(m[4], m[5], m[6], m[7]);

    __syncthreads();

    // ---- Q diag entry for row r ----
    float hv = (r & 1) ? xv[3] : xv[2];
    float sig = (r < 4) ? sigma_p : sigma_v;
    float q = hv * sig;
    q = q * q;

    // ---- x_hat row r ----
    float xh = 0.0f;
#pragma unroll
    for (int j = 0; j < 8; ++j) xh = fmaf(apr[j], xv[j], xh);

    // ---- step 2: out[l] = sum_j apr[j] * M[j][l] + (l==r)*q ----
    float out[8];
#pragma unroll
    for (int l = 0; l < 8; ++l) out[l] = (l == r) ? q : 0.0f;

    const float* ebase = lds_m + e_l * ELEM_STRIDE;
#pragma unroll
    for (int j = 0; j < 8; ++j) {
        const float4* mr = (const float4*)(ebase + j * ROW_STRIDE);
        float4 ma = mr[0], mb = mr[1];
        float mj[8] = {ma.x, ma.y, ma.z, ma.w, mb.x, mb.y, mb.z, mb.w};
#pragma unroll
        for (int l = 0; l < 8; ++l) out[l] = fmaf(apr[j], mj[l], out[l]);
    }

    // ---- stores: x_hat 4B/lane contiguous; P_hat rows cover contiguous 2KB ----
    if (valid) {
        x_hat[(size_t)e * 8 + r] = xh;
        float4* po = (float4*)(P_hat + (size_t)e * 64 + r * 8);
        po[0] = make_float4(out[0], out[1], out[2], out[3]);
        po[1] = make_float4(out[4], out[5], out[6], out[7]);
    }
}

extern "C" void kernel_launch(void* const* d_in, const int* in_sizes, int n_in,
                              void* d_out, int out_size, void* d_ws, size_t ws_size,
                              hipStream_t stream) {
    const float* x  = (const float*)d_in[0];
    const float* P  = (const float*)d_in[1];
    const float* A  = (const float*)d_in[2];
    const float* sp = (const float*)d_in[3];
    const float* sv = (const float*)d_in[4];

    int B = in_sizes[0] / 8;           // x is (B, 8, 1)
    float* x_hat = (float*)d_out;      // B*8 floats
    float* P_hat = (float*)d_out + (size_t)B * 8;  // B*64 floats

    int threads = B * 8;
    int block = 256;
    int grid = (threads + block - 1) / block;
    kalman_predict_kernel<<<grid, block, 0, stream>>>(x, P, A, sp, sv, x_hat, P_hat, B);
}